// Round 10
// baseline (113.611 us; speedup 1.0000x reference)
//
#include <hip/hip_runtime.h>
#include <stdint.h>
#include <stddef.h>

// BalancedFocalLoss fused kernel — MI355X (gfx950), round 10
//
//   z = concat(zx, zy); zn = z/||z||;  sim = zn·znT / 0.5
//   ce_i  = log( sum_{j != i} exp(sim_ij) ) - sim_{i,(i+B)%N}
//   out   = mean( ALPHA * (1-exp(-ce))^2 * ce )
//
// s2n = sqrt(2*log2e)*zn bf16 => acc = log2e*sim; exp(sim) == exp2(acc).
// Upper-triangle 128^2 tiles only (2080); each tile emits row-sums (slot
// q*2+wc) and col-sums (slot p*2+wr) — 128 slots/row, each written once.
//
// R10 (on top of R9's counted-vmcnt pipeline):
//  1. XCD column-band tile ownership: XCD x owns col-bands {15-x, x}
//     (4 panels each; 260 tiles per XCD, exactly balanced). Tiles walked
//     column-major (q fixed, p ascending) -> per-XCD B live set = 512 KB
//     (L2-resident); A streams from L3. Fixes R8/R9's L2 thrash (FETCH 40MB
//     for a 4MB input).
//  2. All partial stores deferred to a kernel-end coalesced flush via a
//     10 KB LDS stash: the loop's vmcnt stream is pure staged loads
//     (in-loop stores made counted vmcnt waits drain 3 steps + stores).
//  3. 4-deep staging buffers (64 KB LDS), vmcnt(12) steady-state: loads
//     land ~4 steps (>=1600 cy) before their wait.

typedef __attribute__((ext_vector_type(8))) short short8;
typedef __attribute__((ext_vector_type(4))) float f32x4;

#define NROWS 8192
#define DDIM 256
#define NBLK 512

__device__ __forceinline__ unsigned short f2bf(float f) {
  unsigned int u = __float_as_uint(f);
  u = (u + 0x7FFFu + ((u >> 16) & 1u)) >> 16;   // RNE, inputs finite
  return (unsigned short)u;
}

// ---------------- 1. normalize + sqrt(2*log2e) scale + bf16; zero d1 counter ----------------
__global__ __launch_bounds__(256) void norm_kernel(const float* __restrict__ zx,
                                                   const float* __restrict__ zy,
                                                   unsigned short* __restrict__ zn,
                                                   unsigned int* __restrict__ counter) {
  if (blockIdx.x == 0 && threadIdx.x == 0) *counter = 0u;
  const int row = blockIdx.x * 4 + (threadIdx.x >> 6);   // 8192 rows, 1 per wave
  const int lane = threadIdx.x & 63;
  const float* src = (row < 4096) ? (zx + (size_t)row * DDIM)
                                  : (zy + (size_t)(row - 4096) * DDIM);
  float4 v = reinterpret_cast<const float4*>(src)[lane];
  float ss = v.x * v.x + v.y * v.y + v.z * v.z + v.w * v.w;
#pragma unroll
  for (int m = 1; m < 64; m <<= 1) ss += __shfl_xor(ss, m);
  const float sc = 1.69864360f * rsqrtf(ss);   // sqrt(2*log2e)/||z||
  ushort4 o;
  o.x = f2bf(v.x * sc); o.y = f2bf(v.y * sc);
  o.z = f2bf(v.z * sc); o.w = f2bf(v.w * sc);
  reinterpret_cast<ushort4*>(zn + (size_t)row * DDIM)[lane] = o;
}

// ---------------- 2. upper-triangle sim GEMM + exp2 row/col sums ----------------
__global__ __launch_bounds__(256, 2) void simtri_kernel(const unsigned short* __restrict__ zn,
                                                        float* __restrict__ partial,
                                                        float* __restrict__ pos) {
  __shared__ unsigned short smem[4][2][128 * 32];   // 64 KiB, 4-deep
  __shared__ float stash[5][4][128];                // 10 KiB deferred partials
  const int x = blockIdx.x & 7;                     // XCD (HW round-robin)
  const int l = blockIdx.x >> 3;                    // 0..63 within XCD
  int r0, nt;                                       // 260 = 4*5 + 60*4
  if (l < 4) { r0 = l * 5;            nt = 5; }
  else       { r0 = 20 + (l - 4) * 4; nt = 4; }
  const int NS = nt * 8;                            // K32-steps

  // Band-pair tile enumeration for this XCD: band b0 = 15-x (cols 4b0..4b0+3)
  // then band b1 = x; within a band, column-major (q fixed, p = 0..q).
  // advance rule: p<q -> ++p; column done: q&3==3 -> jump to band x, else ++q.
  auto advance = [&](int& p, int& q) {
    if (p < q) { ++p; return; }
    p = 0;
    if ((q & 3) == 3) q = 4 * x; else ++q;
  };
  // unrank r0
  int cp = 0, cq = 4 * (15 - x);
  {
    int idx = r0;
    while (true) {
      const int len = cq + 1;
      if (idx < len) { cp = idx; break; }
      idx -= len;
      if ((cq & 3) == 3) cq = 4 * x; else ++cq;
    }
  }
  const int p0 = cp, q0 = cq;

  const int tid = threadIdx.x;
  const int lane = tid & 63;
  const int wid = tid >> 6;
  const int wr = wid >> 1;              // wave row (0/1)
  const int wc = wid & 1;               // wave col (0/1)
  const int hi = lane >> 4, lo = lane & 15;
  const int sw = lo & 3;                // frag-read XOR (== row&3 of this lane's rows)

  const f32x4 z4 = {0.f, 0.f, 0.f, 0.f};
  f32x4 acc[4][4];
#pragma unroll
  for (int m = 0; m < 4; ++m)
#pragma unroll
    for (int n = 0; n < 4; ++n) acc[m][n] = z4;

  // Stage one K32-step of tiles (p,q) into buffer b — always both halves
  // (diag stages B redundantly; constant 8 global_load_lds per wave-pair so
  // counted vmcnt stays exact). LDS dest LINEAR; global source pre-swizzled
  // (unit ul ^ (r&3)); frag reads apply the same XOR (conflict-free).
  auto stage_pair = [&](int b, int p, int q, int k0) {
#pragma unroll
    for (int which = 0; which < 2; ++which) {
      const int row0 = (which ? q : p) << 7;
      unsigned short* lb = &smem[b][which][0];
#pragma unroll
      for (int j = 0; j < 2; ++j) {
        const int u = j * 256 + tid;               // 16B-unit index, 0..511
        const int r = u >> 2, ul = u & 3;          // 4 units per 32-k row
        const unsigned short* g =
            zn + (size_t)(row0 + r) * DDIM + k0 + ((ul ^ (r & 3)) << 3);
        unsigned short* l = lb + (size_t)(j * 256 + wid * 64) * 8;  // wave-uniform
        __builtin_amdgcn_global_load_lds(
            (const __attribute__((address_space(1))) void*)g,
            (__attribute__((address_space(3))) void*)l, 16, 0, 0);
      }
    }
  };

  auto consume = [&](int b) {
    const unsigned short* A = &smem[b][0][0];
    const unsigned short* Bm = &smem[b][1][0];
    short8 af[4], bfr[4];
#pragma unroll
    for (int m = 0; m < 4; ++m)
      af[m] = *reinterpret_cast<const short8*>(
          A + ((wr * 64 + m * 16 + lo) * 32 + ((hi ^ sw) << 3)));
#pragma unroll
    for (int n = 0; n < 4; ++n)
      bfr[n] = *reinterpret_cast<const short8*>(
          Bm + ((wc * 64 + n * 16 + lo) * 32 + ((hi ^ sw) << 3)));
#pragma unroll
    for (int m = 0; m < 4; ++m)
#pragma unroll
      for (int n = 0; n < 4; ++n)
        acc[m][n] = __builtin_amdgcn_mfma_f32_16x16x32_bf16(af[m], bfr[n], acc[m][n], 0, 0, 0);
  };

  // epilogue: exp2, reduce, stash in LDS (NO global stores except rare pos)
  auto epilogue = [&](int tp, int tq, int ti) {
    const bool isdiag = (tp == tq);
    const bool ispos = (tq == tp + 32);
    float rsum[4][4];
    float csum[4];
#pragma unroll
    for (int m = 0; m < 4; ++m)
#pragma unroll
      for (int r = 0; r < 4; ++r) rsum[m][r] = 0.f;
#pragma unroll
    for (int n = 0; n < 4; ++n) csum[n] = 0.f;
#pragma unroll
    for (int m = 0; m < 4; ++m)
#pragma unroll
      for (int n = 0; n < 4; ++n)
#pragma unroll
        for (int r = 0; r < 4; ++r) {
          const float e = __builtin_amdgcn_exp2f(acc[m][n][r]);
          rsum[m][r] += e;
          csum[n] += e;
        }
    if ((isdiag || ispos) && (wr == wc)) {
#pragma unroll
      for (int m = 0; m < 4; ++m)
#pragma unroll
        for (int r = 0; r < 4; ++r)
          if (lo == 4 * hi + r) {
            if (isdiag) rsum[m][r] -= __builtin_amdgcn_exp2f(acc[m][m][r]);
            else        pos[(tp << 7) + wr * 64 + m * 16 + lo] = acc[m][m][r];  // log2-domain
          }
    }
    // row-sums -> stash[ti][wc][rowlocal]
#pragma unroll
    for (int m = 0; m < 4; ++m)
#pragma unroll
      for (int r = 0; r < 4; ++r) {
        float s = rsum[m][r];
        s += __shfl_xor(s, 1); s += __shfl_xor(s, 2);
        s += __shfl_xor(s, 4); s += __shfl_xor(s, 8);
        if (lo == 0) stash[ti][wc][wr * 64 + m * 16 + (hi << 2) + r] = s;
      }
    // col-sums -> stash[ti][2+wr][collocal] (diag: unused)
    if (!isdiag) {
#pragma unroll
      for (int n = 0; n < 4; ++n) {
        float cs = csum[n];
        cs += __shfl_xor(cs, 16); cs += __shfl_xor(cs, 32);
        if (lane < 16) stash[ti][2 + wr][wc * 64 + n * 16 + lane] = cs;
      }
    }
  };

  // ---- pipeline: 4-deep prologue (steps 0..3, all within tile 0) ----
  int sp = cp, sq = cq;
  stage_pair(0, sp, sq, 0);
  stage_pair(1, sp, sq, 32);
  stage_pair(2, sp, sq, 64);
  stage_pair(3, sp, sq, 96);

  int bsel = 0;
  for (int k = 0; k < NS - 3; ++k) {
    asm volatile("s_waitcnt vmcnt(12)" ::: "memory");   // step-k loads done
    __builtin_amdgcn_s_barrier();                       // buf[bsel] complete (all waves)
    __builtin_amdgcn_sched_barrier(0);
    consume(bsel);
    if ((k & 7) == 7) {                                 // tile finished
      epilogue(cp, cq, k >> 3);
      advance(cp, cq);
#pragma unroll
      for (int m = 0; m < 4; ++m)
#pragma unroll
        for (int n = 0; n < 4; ++n) acc[m][n] = z4;
    }
    __builtin_amdgcn_s_barrier();                       // all waves done reading buf[bsel]
    const int t = k + 4;
    if (t < NS) {
      if ((t & 7) == 0) advance(sp, sq);
      stage_pair(bsel, sp, sq, (t & 7) * 32);
    }
    bsel = (bsel + 1) & 3;
  }
  // peeled tail (NS multiple of 8: no epilogue until the last step)
  asm volatile("s_waitcnt vmcnt(8)" ::: "memory");
  __builtin_amdgcn_s_barrier();
  __builtin_amdgcn_sched_barrier(0);
  consume(bsel); bsel = (bsel + 1) & 3;
  asm volatile("s_waitcnt vmcnt(4)" ::: "memory");
  __builtin_amdgcn_s_barrier();
  __builtin_amdgcn_sched_barrier(0);
  consume(bsel); bsel = (bsel + 1) & 3;
  asm volatile("s_waitcnt vmcnt(0)" ::: "memory");
  __builtin_amdgcn_s_barrier();
  __builtin_amdgcn_sched_barrier(0);
  consume(bsel);
  epilogue(cp, cq, nt - 1);

  // ---- coalesced flush of stashed partials ----
  __syncthreads();
  {
    int fp = p0, fq = q0;
    const int half = tid >> 7;          // 0/1
    const int rr = tid & 127;
    for (int i = 0; i < nt; ++i) {
      partial[(size_t)(fq * 2 + half) * NROWS + fp * 128 + rr] = stash[i][half][rr];
      if (fp != fq)
        partial[(size_t)(fp * 2 + half) * NROWS + fq * 128 + rr] = stash[i][2 + half][rr];
      advance(fp, fq);
    }
  }
}

// ---------------- 3. per-row loss + full reduction (last-block-done finish) ----------------
__global__ __launch_bounds__(256) void d1_kernel(const float* __restrict__ partial,
                                                 const float* __restrict__ pos,
                                                 float* __restrict__ bsum,
                                                 float* __restrict__ out,
                                                 unsigned int* __restrict__ counter) {
  const int row = blockIdx.x * 256 + threadIdx.x;   // 32 blocks x 256
  float s = 0.f;
#pragma unroll 16
  for (int c = 0; c < 128; ++c) s += partial[(size_t)c * NROWS + row];
  const float L = __log2f(s) - pos[row & 4095];     // log2-domain ce
  const float pt = __builtin_amdgcn_exp2f(-L);
  const float ce = 0.69314718056f * L;
  float f = (1.f - pt) * (1.f - pt) * ce;
#pragma unroll
  for (int m = 1; m < 64; m <<= 1) f += __shfl_xor(f, m);
  __shared__ float wsum[4];
  if ((threadIdx.x & 63) == 0) wsum[threadIdx.x >> 6] = f;
  __syncthreads();
  if (threadIdx.x == 0) {
    bsum[blockIdx.x] = wsum[0] + wsum[1] + wsum[2] + wsum[3];
    __threadfence();
    if (atomicAdd(counter, 1u) == 31u) {        // last block: deterministic finish
      __threadfence();
      float v = 0.f;
#pragma unroll
      for (int c = 0; c < 32; ++c) v += ((const volatile float*)bsum)[c];
      out[0] = 0.25f * v / 8192.f;              // ALPHA * mean
    }
  }
}

extern "C" void kernel_launch(void* const* d_in, const int* in_sizes, int n_in,
                              void* d_out, int out_size, void* d_ws, size_t ws_size,
                              hipStream_t stream) {
  const float* zx = (const float*)d_in[0];
  const float* zy = (const float*)d_in[1];
  float* out = (float*)d_out;

  // workspace (~8.02 MiB): zn bf16 | pos | partial | bsum | counter
  unsigned short* zn = (unsigned short*)d_ws;                      // 8192*256*2 = 4 MiB
  float* pos = (float*)((char*)d_ws + (size_t)NROWS * DDIM * 2);   // 16 KiB
  float* partial = pos + 4096;                                     // 128*8192*4 = 4 MiB
  float* bsum = partial + (size_t)128 * NROWS;                     // 128 B
  unsigned int* counter = (unsigned int*)(bsum + 32);              // 4 B

  norm_kernel<<<2048, 256, 0, stream>>>(zx, zy, zn, counter);
  simtri_kernel<<<NBLK, 256, 0, stream>>>(zn, partial, pos);
  d1_kernel<<<32, 256, 0, stream>>>(partial, pos, bsum, out, counter);
}

// Round 11
// 108.722 us; speedup vs baseline: 1.0450x; 1.0450x over previous
//
#include <hip/hip_runtime.h>
#include <stdint.h>
#include <stddef.h>

// BalancedFocalLoss fused kernel — MI355X (gfx950), round 11
//
//   z = concat(zx, zy); zn = z/||z||;  sim = zn·znT / 0.5
//   ce_i  = log( sum_{j != i} exp(sim_ij) ) - sim_{i,(i+B)%N}
//   out   = mean( ALPHA * (1-exp(-ce))^2 * ce )
//
// s2n = sqrt(2*log2e)*zn bf16 => acc = log2e*sim; exp(sim) == exp2(acc).
// Upper-triangle 128^2 tiles (2080); tile (p,q) emits row-sums (slot q*2+wc)
// and col-sums (slot p*2+wr) — per row, 128 slots each written exactly once.
//
// R11 = cleaned R5 (the measured-best structure: BK=64, ONE barrier per
// K-step, 2 blocks/CU). Cross-round regression R1..R10 showed per-tile time
// tracks barrier count (4/tile best), NOT occupancy/drain-style/locality.
// Fixes vs R5: (1) pair-column enumeration — pair (q,63-q) = 65 tiles; XCD x
// owns pairs 4x..4x+3 (260 tiles exactly) -> balanced XCDs + B-panel L2
// locality; (2) the 32 five-tile chunks spread 4-per-XCD on distinct CUs
// (R5 put them all on XCD 0: +25% tail); (3) partial stores deferred to a
// coalesced end-flush via 10 KiB LDS stash; (4) diag tiles skip B staging.

typedef __attribute__((ext_vector_type(8))) short short8;
typedef __attribute__((ext_vector_type(4))) float f32x4;

#define NROWS 8192
#define DDIM 256
#define NBLK 512

__device__ __forceinline__ unsigned short f2bf(float f) {
  unsigned int u = __float_as_uint(f);
  u = (u + 0x7FFFu + ((u >> 16) & 1u)) >> 16;   // RNE, inputs finite
  return (unsigned short)u;
}

// ---------------- 1. normalize + sqrt(2*log2e) scale + bf16; zero d1 counter ----------------
__global__ __launch_bounds__(256) void norm_kernel(const float* __restrict__ zx,
                                                   const float* __restrict__ zy,
                                                   unsigned short* __restrict__ zn,
                                                   unsigned int* __restrict__ counter) {
  if (blockIdx.x == 0 && threadIdx.x == 0) *counter = 0u;
  const int row = blockIdx.x * 4 + (threadIdx.x >> 6);   // 8192 rows, 1 per wave
  const int lane = threadIdx.x & 63;
  const float* src = (row < 4096) ? (zx + (size_t)row * DDIM)
                                  : (zy + (size_t)(row - 4096) * DDIM);
  float4 v = reinterpret_cast<const float4*>(src)[lane];
  float ss = v.x * v.x + v.y * v.y + v.z * v.z + v.w * v.w;
#pragma unroll
  for (int m = 1; m < 64; m <<= 1) ss += __shfl_xor(ss, m);
  const float sc = 1.69864360f * rsqrtf(ss);   // sqrt(2*log2e)/||z||
  ushort4 o;
  o.x = f2bf(v.x * sc); o.y = f2bf(v.y * sc);
  o.z = f2bf(v.z * sc); o.w = f2bf(v.w * sc);
  reinterpret_cast<ushort4*>(zn + (size_t)row * DDIM)[lane] = o;
}

// ---------------- 2. upper-triangle sim GEMM + exp2 row/col sums ----------------
// Tile enumeration: pairs j=0..31 of columns (qa=j: p=0..j) then (qb=63-j:
// p=0..63-j), 65 tiles/pair, rank-contiguous. XCD x (bid&7) owns ranks
// [260x, 260x+260) = pairs 4x..4x+3.
__global__ __launch_bounds__(256, 2) void simtri_kernel(const unsigned short* __restrict__ zn,
                                                        float* __restrict__ partial,
                                                        float* __restrict__ pos) {
  __shared__ unsigned short smem[2][2][128 * 64];   // 64 KiB double-buffer
  __shared__ float stash[5][4][128];                // 10 KiB deferred partials
  // chunk id: XCD-contiguous (same-XCD blocks -> consecutive ranks)
  const int c = (blockIdx.x & 7) * 64 + (blockIdx.x >> 3);
  const int cl = c & 63;
  // 5-tile chunks at cl in {0,16,32,48} (4 per XCD, distinct CUs); rest 4.
  const int nt = ((cl & 15) == 0) ? 5 : 4;
  const int start = 4 * c + 4 * (c >> 6) + ((cl + 15) >> 4);

  // unrank: pair j = t/65, r = t%65; r<=j -> (r, j) else (r-j-1, 63-j)
  int cp, cq;
  {
    const int j = start / 65, r = start - j * 65;
    if (r <= j) { cp = r; cq = j; } else { cp = r - j - 1; cq = 63 - j; }
  }
  const int p0 = cp, q0 = cq;
  // advance within pair-column order
  auto advance = [&](int& p, int& q) {
    if (p < q) { ++p; return; }
    p = 0;
    q = (q < 32) ? (63 - q) : (64 - q);
  };

  const int tid = threadIdx.x;
  const int lane = tid & 63;
  const int wid = tid >> 6;
  const int wr = wid >> 1;              // wave row (0/1)
  const int wc = wid & 1;               // wave col (0/1)
  const int hi = lane >> 4, lo = lane & 15;
  const int sw = lo & 7;                // frag-read XOR (== row&7 of this lane's rows)

  const f32x4 z4 = {0.f, 0.f, 0.f, 0.f};
  f32x4 acc[4][4];
#pragma unroll
  for (int m = 0; m < 4; ++m)
#pragma unroll
    for (int n = 0; n < 4; ++n) acc[m][n] = z4;

  // Stage 128x64 bf16 tile: LDS dest LINEAR (global_load_lds requirement);
  // global source pre-swizzled so LDS[r][ul] holds unit (ul ^ (r&7)); frag
  // reads apply the same XOR -> bank-conflict-free b128 (8-phase minimum).
  auto stage_one = [&](int buf, int which, int row0, int k0) {
    unsigned short* lb = &smem[buf][which][0];
#pragma unroll
    for (int j = 0; j < 4; ++j) {
      const int u = j * 256 + tid;                 // 16B-unit index, 0..1023
      const int r = u >> 3, ul = u & 7;
      const unsigned short* g =
          zn + (size_t)(row0 + r) * DDIM + k0 + ((ul ^ (r & 7)) << 3);
      unsigned short* l = lb + (size_t)(j * 256 + wid * 64) * 8;  // wave-uniform
      __builtin_amdgcn_global_load_lds(
          (const __attribute__((address_space(1))) void*)g,
          (__attribute__((address_space(3))) void*)l, 16, 0, 0);
    }
  };
  auto stageT = [&](int buf, int p, int q, int k0) {
    stage_one(buf, 0, p << 7, k0);
    if (p != q) stage_one(buf, 1, q << 7, k0);
  };

  stageT(0, cp, cq, 0);
  __syncthreads();

  int buf = 0;
  for (int i = 0; i < nt; ++i) {
    int np = cp, nq = cq;
    const bool have_next = (i + 1 < nt);
    if (have_next) advance(np, nq);
    const bool isdiag = (cp == cq);
    const bool ispos = (cq == cp + 32);
    const int R0 = cp << 7;

#pragma unroll
    for (int kk = 0; kk < 4; ++kk) {
      if (kk < 3) stageT(buf ^ 1, cp, cq, (kk + 1) * 64);
      else if (have_next) stageT(buf ^ 1, np, nq, 0);
      const unsigned short* A = &smem[buf][0][0];
      const unsigned short* Bm = isdiag ? A : &smem[buf][1][0];
#pragma unroll
      for (int ks = 0; ks < 2; ++ks) {
        short8 af[4], bfr[4];
#pragma unroll
        for (int m = 0; m < 4; ++m)
          af[m] = *reinterpret_cast<const short8*>(
              A + ((wr * 64 + m * 16 + lo) * 64 + (((ks * 4 + hi) ^ sw) << 3)));
#pragma unroll
        for (int n = 0; n < 4; ++n)
          bfr[n] = *reinterpret_cast<const short8*>(
              Bm + ((wc * 64 + n * 16 + lo) * 64 + (((ks * 4 + hi) ^ sw) << 3)));
#pragma unroll
        for (int m = 0; m < 4; ++m)
#pragma unroll
          for (int n = 0; n < 4; ++n)
            acc[m][n] = __builtin_amdgcn_mfma_f32_16x16x32_bf16(af[m], bfr[n], acc[m][n], 0, 0, 0);
      }
      buf ^= 1;
      if (kk < 3) __syncthreads();     // ONE barrier per K-step
    }

    // ---- epilogue (before the tile-boundary barrier: hides next stage) ----
    float rsum[4][4];
    float csum[4];
#pragma unroll
    for (int m = 0; m < 4; ++m)
#pragma unroll
      for (int r = 0; r < 4; ++r) rsum[m][r] = 0.f;
#pragma unroll
    for (int n = 0; n < 4; ++n) csum[n] = 0.f;
#pragma unroll
    for (int m = 0; m < 4; ++m)
#pragma unroll
      for (int n = 0; n < 4; ++n)
#pragma unroll
        for (int r = 0; r < 4; ++r) {
          const float e = __builtin_amdgcn_exp2f(acc[m][n][r]);
          rsum[m][r] += e;
          csum[n] += e;
        }
    if ((isdiag || ispos) && (wr == wc)) {
#pragma unroll
      for (int m = 0; m < 4; ++m)
#pragma unroll
        for (int r = 0; r < 4; ++r)
          if (lo == 4 * hi + r) {
            if (isdiag) rsum[m][r] -= __builtin_amdgcn_exp2f(acc[m][m][r]);
            else        pos[R0 + wr * 64 + m * 16 + lo] = acc[m][m][r];  // log2-domain
          }
    }
    // row-sums -> stash[i][wc][.]
#pragma unroll
    for (int m = 0; m < 4; ++m)
#pragma unroll
      for (int r = 0; r < 4; ++r) {
        float s = rsum[m][r];
        s += __shfl_xor(s, 1); s += __shfl_xor(s, 2);
        s += __shfl_xor(s, 4); s += __shfl_xor(s, 8);
        if (lo == 0) stash[i][wc][wr * 64 + m * 16 + (hi << 2) + r] = s;
      }
    // col-sums -> stash[i][2+wr][.] (diag tile: unused)
    if (!isdiag) {
#pragma unroll
      for (int n = 0; n < 4; ++n) {
        float cs = csum[n];
        cs += __shfl_xor(cs, 16); cs += __shfl_xor(cs, 32);
        if (lane < 16) stash[i][2 + wr][wc * 64 + n * 16 + lane] = cs;
      }
    }

#pragma unroll
    for (int m = 0; m < 4; ++m)
#pragma unroll
      for (int n = 0; n < 4; ++n) acc[m][n] = z4;

    __syncthreads();   // next-tile staged data ready; old buf safe to overwrite
    cp = np; cq = nq;
  }

  // ---- coalesced flush of stashed partials ----
  __syncthreads();
  {
    int fp = p0, fq = q0;
    const int half = tid >> 7;          // 0/1
    const int rr = tid & 127;
    for (int i = 0; i < nt; ++i) {
      partial[(size_t)(fq * 2 + half) * NROWS + fp * 128 + rr] = stash[i][half][rr];
      if (fp != fq)
        partial[(size_t)(fp * 2 + half) * NROWS + fq * 128 + rr] = stash[i][2 + half][rr];
      advance(fp, fq);
    }
  }
}

// ---------------- 3. per-row loss + full reduction (last-block-done finish) ----------------
__global__ __launch_bounds__(256) void d1_kernel(const float* __restrict__ partial,
                                                 const float* __restrict__ pos,
                                                 float* __restrict__ bsum,
                                                 float* __restrict__ out,
                                                 unsigned int* __restrict__ counter) {
  const int row = blockIdx.x * 256 + threadIdx.x;   // 32 blocks x 256
  float s = 0.f;
#pragma unroll 16
  for (int c = 0; c < 128; ++c) s += partial[(size_t)c * NROWS + row];
  const float L = __log2f(s) - pos[row & 4095];     // log2-domain ce
  const float pt = __builtin_amdgcn_exp2f(-L);
  const float ce = 0.69314718056f * L;
  float f = (1.f - pt) * (1.f - pt) * ce;
#pragma unroll
  for (int m = 1; m < 64; m <<= 1) f += __shfl_xor(f, m);
  __shared__ float wsum[4];
  if ((threadIdx.x & 63) == 0) wsum[threadIdx.x >> 6] = f;
  __syncthreads();
  if (threadIdx.x == 0) {
    bsum[blockIdx.x] = wsum[0] + wsum[1] + wsum[2] + wsum[3];
    __threadfence();
    if (atomicAdd(counter, 1u) == 31u) {        // last block: deterministic finish
      __threadfence();
      float v = 0.f;
#pragma unroll
      for (int c = 0; c < 32; ++c) v += ((const volatile float*)bsum)[c];
      out[0] = 0.25f * v / 8192.f;              // ALPHA * mean
    }
  }
}

extern "C" void kernel_launch(void* const* d_in, const int* in_sizes, int n_in,
                              void* d_out, int out_size, void* d_ws, size_t ws_size,
                              hipStream_t stream) {
  const float* zx = (const float*)d_in[0];
  const float* zy = (const float*)d_in[1];
  float* out = (float*)d_out;

  // workspace (~8.02 MiB): zn bf16 | pos | partial | bsum | counter
  unsigned short* zn = (unsigned short*)d_ws;                      // 8192*256*2 = 4 MiB
  float* pos = (float*)((char*)d_ws + (size_t)NROWS * DDIM * 2);   // 16 KiB
  float* partial = pos + 4096;                                     // 128*8192*4 = 4 MiB
  float* bsum = partial + (size_t)128 * NROWS;                     // 128 B
  unsigned int* counter = (unsigned int*)(bsum + 32);              // 4 B

  norm_kernel<<<2048, 256, 0, stream>>>(zx, zy, zn, counter);
  simtri_kernel<<<NBLK, 256, 0, stream>>>(zn, partial, pos);
  d1_kernel<<<32, 256, 0, stream>>>(partial, pos, bsum, out, counter);
}